// Round 13
// baseline (287.797 us; speedup 1.0000x reference)
//
#include <hip/hip_runtime.h>

#define NC 91
#define NB 32
#define HW (1024 * 1024)

#define THREADS 256
#define PPT 64                          // pixels per thread
#define PIX_PER_BLOCK (THREADS * PPT)   // 16384
#define CHUNKS (HW / PIX_PER_BLOCK)     // 64 blocks per batch
#define NPAIR (NC * NC)                 // 8281 joint bins
#define NWORD ((NPAIR + 1) / 2)         // 4141 packed words = 16,564 B

// Round-13: DS-BATCHING. Model from rounds 0-12 + r10 ablation: a scattered
// ds_add whose address depends on a just-finished vmcnt wait issues alone and
// pays ~120 cyc of unoverlapped DS latency; 4 such per wave-iteration = 480
// cyc x 512 wave-iters/CU = 102 us — the invariant wall (fits r3/r4/r9/r12;
// ctrl_ds's 64 back-to-back register-fed atomics pipeline at ~12 cyc).
// Fix: per wave, load 16 px (8 dwordx4) per batch -> ONE wait -> 16 bins ->
// 16 CONSECUTIVE ds_adds (pipelined), 4 batches total. Per batch ~120+15*12
// ~= 300 cyc vs 624 now, and 8 loads in flight per wait instead of 2.
// Histogram unchanged: packed 16-bit pair hist (max/bin 16384 < 2^16).

__global__ __launch_bounds__(256, 8) void hist_kernel(const int* __restrict__ x,
                                                      const int* __restrict__ t,
                                                      int* __restrict__ g_cx,
                                                      int* __restrict__ g_ct,
                                                      int* __restrict__ g_in) {
    __shared__ int s_pair[NWORD];   // 16,564 B, 2 bins/word (16-bit fields)

    const int tid = threadIdx.x;
    for (int j = tid; j < NWORD; j += THREADS) s_pair[j] = 0;
    __syncthreads();

    const int b = blockIdx.y;
    const long base = (long)b * HW + (long)blockIdx.x * PIX_PER_BLOCK;
    const int4* __restrict__ x4 = (const int4*)(x + base);
    const int4* __restrict__ t4 = (const int4*)(t + base);

#pragma unroll
    for (int bt = 0; bt < 4; ++bt) {
        // ---- load phase: 8 independent dwordx4 (16 px), one wait ----
        const int j0 = bt * 4;
        const int4 xa = x4[(j0 + 0) * THREADS + tid];
        const int4 xb = x4[(j0 + 1) * THREADS + tid];
        const int4 xc = x4[(j0 + 2) * THREADS + tid];
        const int4 xd = x4[(j0 + 3) * THREADS + tid];
        const int4 ta = t4[(j0 + 0) * THREADS + tid];
        const int4 tb = t4[(j0 + 1) * THREADS + tid];
        const int4 tc = t4[(j0 + 2) * THREADS + tid];
        const int4 td = t4[(j0 + 3) * THREADS + tid];

        // ---- bin phase: 16 packed-bin (word, incr) pairs, straight-line ----
        const int b00 = xa.x * NC + ta.x, b01 = xa.y * NC + ta.y;
        const int b02 = xa.z * NC + ta.z, b03 = xa.w * NC + ta.w;
        const int b04 = xb.x * NC + tb.x, b05 = xb.y * NC + tb.y;
        const int b06 = xb.z * NC + tb.z, b07 = xb.w * NC + tb.w;
        const int b08 = xc.x * NC + tc.x, b09 = xc.y * NC + tc.y;
        const int b10 = xc.z * NC + tc.z, b11 = xc.w * NC + tc.w;
        const int b12 = xd.x * NC + td.x, b13 = xd.y * NC + td.y;
        const int b14 = xd.z * NC + td.z, b15 = xd.w * NC + td.w;

        // ---- DS phase: 16 consecutive fire-and-forget ds_adds ----
        atomicAdd(&s_pair[b00 >> 1], 1 << ((b00 & 1) << 4));
        atomicAdd(&s_pair[b01 >> 1], 1 << ((b01 & 1) << 4));
        atomicAdd(&s_pair[b02 >> 1], 1 << ((b02 & 1) << 4));
        atomicAdd(&s_pair[b03 >> 1], 1 << ((b03 & 1) << 4));
        atomicAdd(&s_pair[b04 >> 1], 1 << ((b04 & 1) << 4));
        atomicAdd(&s_pair[b05 >> 1], 1 << ((b05 & 1) << 4));
        atomicAdd(&s_pair[b06 >> 1], 1 << ((b06 & 1) << 4));
        atomicAdd(&s_pair[b07 >> 1], 1 << ((b07 & 1) << 4));
        atomicAdd(&s_pair[b08 >> 1], 1 << ((b08 & 1) << 4));
        atomicAdd(&s_pair[b09 >> 1], 1 << ((b09 & 1) << 4));
        atomicAdd(&s_pair[b10 >> 1], 1 << ((b10 & 1) << 4));
        atomicAdd(&s_pair[b11 >> 1], 1 << ((b11 & 1) << 4));
        atomicAdd(&s_pair[b12 >> 1], 1 << ((b12 & 1) << 4));
        atomicAdd(&s_pair[b13 >> 1], 1 << ((b13 & 1) << 4));
        atomicAdd(&s_pair[b14 >> 1], 1 << ((b14 & 1) << 4));
        atomicAdd(&s_pair[b15 >> 1], 1 << ((b15 & 1) << 4));
    }
    __syncthreads();

    // Epilogue: fold the packed joint histogram into its three marginals.
    if (tid < NC) {
        int ct = 0;
        for (int xx = 0; xx < NC; ++xx) {
            const int bin = xx * NC + tid;
            ct += (s_pair[bin >> 1] >> ((bin & 1) << 4)) & 0xffff;
        }
        if (ct) atomicAdd(&g_ct[b * NC + tid], ct);
        // diag bin = tid*92: always even parity -> lo field
        const int dg = s_pair[tid * 46] & 0xffff;
        if (dg) atomicAdd(&g_in[b * NC + tid], dg);
    } else if (tid >= 128 && tid < 128 + NC) {
        const int c = tid - 128;
        int cx = 0;
        for (int tt = 0; tt < NC; ++tt) {
            const int bin = c * NC + tt;
            cx += (s_pair[bin >> 1] >> ((bin & 1) << 4)) & 0xffff;
        }
        if (cx) atomicAdd(&g_cx[b * NC + c], cx);
    }
}

__global__ __launch_bounds__(64) void finalize_kernel(const int* __restrict__ g_cx,
                                                      const int* __restrict__ g_ct,
                                                      const int* __restrict__ g_in,
                                                      const float* __restrict__ smooth,
                                                      float* __restrict__ out) {
    const int b = blockIdx.x;
    const int lane = threadIdx.x;  // 0..63
    const float s = smooth[0];
    float acc = 0.0f;
    for (int c = lane; c < NC; c += 64) {
        const float in = (float)g_in[b * NC + c];
        const float un = (float)(g_cx[b * NC + c] + g_ct[b * NC + c]) - in;
        acc += (in + s) / (un + s);
    }
#pragma unroll
    for (int off = 32; off > 0; off >>= 1)
        acc += __shfl_down(acc, off, 64);
    if (lane == 0) out[b] = acc / (float)NC;
}

extern "C" void kernel_launch(void* const* d_in, const int* in_sizes, int n_in,
                              void* d_out, int out_size, void* d_ws, size_t ws_size,
                              hipStream_t stream) {
    const int* x = (const int*)d_in[0];
    const int* t = (const int*)d_in[1];
    const float* smooth = (const float*)d_in[2];
    float* out = (float*)d_out;

    int* g_cx = (int*)d_ws;                   // NB*NC
    int* g_ct = g_cx + NB * NC;               // NB*NC
    int* g_in = g_ct + NB * NC;               // NB*NC

    hipMemsetAsync(d_ws, 0, 3 * NB * NC * sizeof(int), stream);

    dim3 grid(CHUNKS, NB);  // 64 x 32 = 2048 blocks (8/CU)
    hist_kernel<<<grid, THREADS, 0, stream>>>(x, t, g_cx, g_ct, g_in);
    finalize_kernel<<<NB, 64, 0, stream>>>(g_cx, g_ct, g_in, smooth, out);
}

// Round 14
// 284.828 us; speedup vs baseline: 1.0104x; 1.0104x over previous
//
#include <hip/hip_runtime.h>

#define NC 91
#define NB 32
#define HW (1024 * 1024)

#define THREADS 256
#define PIX_PER_BLOCK 16384
#define GRID_X (HW / PIX_PER_BLOCK)     // 64 blocks per batch image
#define CPX 2048                        // pixels per staged chunk
#define NCHUNK (PIX_PER_BLOCK / CPX)    // 8 chunks per block
#define NPAIR (NC * NC)                 // 8281 joint bins
#define NWORD ((NPAIR + 1) / 2)         // 4141 packed words = 16,564 B

// Round-14: DMA STAGING (global_load_lds) to break the MLP wall.
// Diagnosis from 14 structures + r10 ablation + r13 VGPR=28: every variant
// was memory-latency-bound at ~2.4 TB/s effective input BW because the
// compiler's register-lean schedule keeps only ~4-6 loads in flight/wave
// (chip-wide ~0.5 MB << 2.4 MB bandwidth-delay product at ~900cy HBM lat).
// DS op count/type/conflicts/occupancy were never the limiter (ctrl_ds:
// 2048 wave-atomics/CU ~ 10 us; ctrl_mem: same load pattern ~ 6+ TB/s).
// Fix: stage x/t chunks into LDS via fire-and-forget 16B global_load_lds
// (4 KB in flight per wave -> ~12 MB chip-wide), double-buffered; compute
// phase is pure-LDS (ds_read_b128 labels + 1 packed ds_add/px into the
// 16-bit pair histogram). __syncthreads()'s vmcnt(0) drain sits AFTER a
// full compute phase, so DMA latency hides under compute.

typedef __attribute__((address_space(3))) void lds_t;
typedef __attribute__((address_space(1))) const void gm_t;

__device__ __forceinline__ void dma16(const int* g, int* l) {
    // HW semantics: LDS dest = wave-uniform base + lane*16B; global src per-lane.
    __builtin_amdgcn_global_load_lds((gm_t*)g, (lds_t*)l, 16, 0, 0);
}

__global__ __launch_bounds__(256) void hist_kernel(const int* __restrict__ x,
                                                   const int* __restrict__ t,
                                                   int* __restrict__ g_cx,
                                                   int* __restrict__ g_ct,
                                                   int* __restrict__ g_in) {
    __shared__ int s_pair[NWORD];          // 16,564 B packed pair histogram
    __shared__ int s_stage[2][2][CPX];     // [buf][x/t][px] = 32 KB staging

    const int tid = threadIdx.x;
    const int lane = tid & 63;
    const int wid = tid >> 6;              // wave id 0..3

    for (int j = tid; j < NWORD; j += THREADS) s_pair[j] = 0;

    const int b = blockIdx.y;
    const long base = (long)b * HW + (long)blockIdx.x * PIX_PER_BLOCK;
    const int* __restrict__ xg = x + base;
    const int* __restrict__ tg = t + base;

    // --- DMA issue for chunk c into buffer bf: wave wid covers 256-px slabs
    //     j = wid*2+k; per instr: 64 lanes x 16B = 1 KB (256 px). ---
#define ISSUE(c, bf)                                                      \
    {                                                                     \
        _Pragma("unroll")                                                 \
        for (int k = 0; k < 2; ++k) {                                     \
            const int j = wid * 2 + k;                                    \
            const int off = (c) * CPX + j * 256 + lane * 4;               \
            dma16(xg + off, &s_stage[bf][0][j * 256]);                    \
            dma16(tg + off, &s_stage[bf][1][j * 256]);                    \
        }                                                                 \
    }

    ISSUE(0, 0)
    __syncthreads();   // drains vmcnt(0): chunk 0 staged; s_pair zeroed

    for (int c = 0; c < NCHUNK; ++c) {
        const int bf = c & 1;
        if (c + 1 < NCHUNK) ISSUE(c + 1, bf ^ 1)   // fire-and-forget, deep queue

        // compute phase: pure LDS. 8 px/thread: 2 int4 of x + 2 int4 of t.
        const int4* __restrict__ xs = (const int4*)s_stage[bf][0];
        const int4* __restrict__ ts = (const int4*)s_stage[bf][1];
#pragma unroll
        for (int r = 0; r < 2; ++r) {
            const int4 xv = xs[r * 256 + tid];
            const int4 tv = ts[r * 256 + tid];
            const int b0 = xv.x * NC + tv.x;
            const int b1 = xv.y * NC + tv.y;
            const int b2 = xv.z * NC + tv.z;
            const int b3 = xv.w * NC + tv.w;
            atomicAdd(&s_pair[b0 >> 1], 1 << ((b0 & 1) << 4));
            atomicAdd(&s_pair[b1 >> 1], 1 << ((b1 & 1) << 4));
            atomicAdd(&s_pair[b2 >> 1], 1 << ((b2 & 1) << 4));
            atomicAdd(&s_pair[b3 >> 1], 1 << ((b3 & 1) << 4));
        }
        // barrier: (a) all reads of buf[bf] done before it's re-DMA'd next
        // iter; (b) vmcnt(0) drain -> chunk c+1 fully staged (DMA latency
        // was hidden under this compute phase).
        __syncthreads();
    }

    // Epilogue: fold the packed joint histogram into its three marginals.
    if (tid < NC) {
        int ct = 0;
        for (int xx = 0; xx < NC; ++xx) {
            const int bin = xx * NC + tid;
            ct += (s_pair[bin >> 1] >> ((bin & 1) << 4)) & 0xffff;
        }
        if (ct) atomicAdd(&g_ct[b * NC + tid], ct);
        // diag bin = tid*92: always even parity -> lo field
        const int dg = s_pair[tid * 46] & 0xffff;
        if (dg) atomicAdd(&g_in[b * NC + tid], dg);
    } else if (tid >= 128 && tid < 128 + NC) {
        const int c = tid - 128;
        int cx = 0;
        for (int tt = 0; tt < NC; ++tt) {
            const int bin = c * NC + tt;
            cx += (s_pair[bin >> 1] >> ((bin & 1) << 4)) & 0xffff;
        }
        if (cx) atomicAdd(&g_cx[b * NC + c], cx);
    }
#undef ISSUE
}

__global__ __launch_bounds__(64) void finalize_kernel(const int* __restrict__ g_cx,
                                                      const int* __restrict__ g_ct,
                                                      const int* __restrict__ g_in,
                                                      const float* __restrict__ smooth,
                                                      float* __restrict__ out) {
    const int b = blockIdx.x;
    const int lane = threadIdx.x;  // 0..63
    const float s = smooth[0];
    float acc = 0.0f;
    for (int c = lane; c < NC; c += 64) {
        const float in = (float)g_in[b * NC + c];
        const float un = (float)(g_cx[b * NC + c] + g_ct[b * NC + c]) - in;
        acc += (in + s) / (un + s);
    }
#pragma unroll
    for (int off = 32; off > 0; off >>= 1)
        acc += __shfl_down(acc, off, 64);
    if (lane == 0) out[b] = acc / (float)NC;
}

extern "C" void kernel_launch(void* const* d_in, const int* in_sizes, int n_in,
                              void* d_out, int out_size, void* d_ws, size_t ws_size,
                              hipStream_t stream) {
    const int* x = (const int*)d_in[0];
    const int* t = (const int*)d_in[1];
    const float* smooth = (const float*)d_in[2];
    float* out = (float*)d_out;

    int* g_cx = (int*)d_ws;                   // NB*NC
    int* g_ct = g_cx + NB * NC;               // NB*NC
    int* g_in = g_ct + NB * NC;               // NB*NC

    hipMemsetAsync(d_ws, 0, 3 * NB * NC * sizeof(int), stream);

    dim3 grid(GRID_X, NB);  // 64 x 32 = 2048 blocks (3/CU resident)
    hist_kernel<<<grid, THREADS, 0, stream>>>(x, t, g_cx, g_ct, g_in);
    finalize_kernel<<<NB, 64, 0, stream>>>(g_cx, g_ct, g_in, smooth, out);
}

// Round 15
// 282.558 us; speedup vs baseline: 1.0185x; 1.0080x over previous
//
#include <hip/hip_runtime.h>

#define NC 91
#define NB 32
#define HW (1024 * 1024)

#define THREADS 256
#define PIX_PER_BLOCK 16384
#define GRID_X (HW / PIX_PER_BLOCK)     // 64 blocks per batch image
#define CPX 4096                        // pixels per phase
#define NPHASE (PIX_PER_BLOCK / CPX)    // 4 phases per block
#define NPAIR (NC * NC)                 // 8281 joint bins
#define NWORD ((NPAIR + 1) / 2)         // 4141 packed words = 16,564 B

// Round-15: PHASE SEPARATION — the pre-registered round-10 readout-(c)
// experiment, never actually run. Ledger: ctrl_mem (VMEM only) ~44 us at
// ~6 TB/s; ctrl_ds (DS only) ~10 us; every kernel that keeps VMEM and
// data-dependent DS ops in flight CONCURRENTLY sits at 102-110 us
// (~2.5 TB/s), invariant to DS count/type, conflicts, occupancy, batching,
// and DMA staging. Hypothesis: VMEM<->DS concurrency itself is the wall.
// Fix/test: strictly serialize at block level —
//   load phase:  global_load_lds only (no DS ops in flight), barrier
//   compute phase: pure LDS (ds_read_b128 + 1 packed ds_add/px), barrier
// Single staging buffer (NO double-buffer): intra-block overlap is the
// suspected poison; the 3 resident blocks/CU desync and pipeline the pipes
// against each other instead. Hist core unchanged from verified r12.

typedef __attribute__((address_space(3))) void lds_t;
typedef __attribute__((address_space(1))) const void gm_t;

__device__ __forceinline__ void dma16(const int* g, int* l) {
    // LDS dest = wave-uniform base + lane*16B; global src is per-lane.
    __builtin_amdgcn_global_load_lds((gm_t*)g, (lds_t*)l, 16, 0, 0);
}

__global__ __launch_bounds__(256) void hist_kernel(const int* __restrict__ x,
                                                   const int* __restrict__ t,
                                                   int* __restrict__ g_cx,
                                                   int* __restrict__ g_ct,
                                                   int* __restrict__ g_in) {
    __shared__ int s_pair[NWORD];   // 16,564 B packed pair histogram
    __shared__ int s_sx[CPX];       // 16 KB staged x labels
    __shared__ int s_st[CPX];       // 16 KB staged t labels

    const int tid = threadIdx.x;
    const int lane = tid & 63;
    const int wid = tid >> 6;       // wave id 0..3

    for (int j = tid; j < NWORD; j += THREADS) s_pair[j] = 0;

    const int b = blockIdx.y;
    const long base = (long)b * HW + (long)blockIdx.x * PIX_PER_BLOCK;
    const int* __restrict__ xg = x + base;
    const int* __restrict__ tg = t + base;

    for (int p = 0; p < NPHASE; ++p) {
        // ---- LOAD PHASE: 4096 px of x and t, DMA only, no DS ops. ----
        // 16 slabs of 256 px per array; wave wid covers slabs wid*4..wid*4+3.
#pragma unroll
        for (int k = 0; k < 4; ++k) {
            const int j = wid * 4 + k;
            const int off = p * CPX + j * 256 + lane * 4;
            dma16(xg + off, &s_sx[j * 256]);
            dma16(tg + off, &s_st[j * 256]);
        }
        // Barrier drains vmcnt(0): staging complete. (First iteration also
        // covers the s_pair zeroing.) No DS ops were in flight during DMA.
        __syncthreads();

        // ---- COMPUTE PHASE: pure LDS, no VMEM in flight. 16 px/thread. ----
        const int4* __restrict__ xs = (const int4*)s_sx;
        const int4* __restrict__ ts = (const int4*)s_st;
#pragma unroll
        for (int r = 0; r < 4; ++r) {
            const int4 xv = xs[r * 256 + tid];
            const int4 tv = ts[r * 256 + tid];
            const int b0 = xv.x * NC + tv.x;
            const int b1 = xv.y * NC + tv.y;
            const int b2 = xv.z * NC + tv.z;
            const int b3 = xv.w * NC + tv.w;
            atomicAdd(&s_pair[b0 >> 1], 1 << ((b0 & 1) << 4));
            atomicAdd(&s_pair[b1 >> 1], 1 << ((b1 & 1) << 4));
            atomicAdd(&s_pair[b2 >> 1], 1 << ((b2 & 1) << 4));
            atomicAdd(&s_pair[b3 >> 1], 1 << ((b3 & 1) << 4));
        }
        __syncthreads();   // staging safe to overwrite in next load phase
    }

    // Epilogue (verified in r12): fold packed joint histogram into marginals.
    if (tid < NC) {
        int ct = 0;
        for (int xx = 0; xx < NC; ++xx) {
            const int bin = xx * NC + tid;
            ct += (s_pair[bin >> 1] >> ((bin & 1) << 4)) & 0xffff;
        }
        if (ct) atomicAdd(&g_ct[b * NC + tid], ct);
        // diag bin = tid*92: always even parity -> lo field
        const int dg = s_pair[tid * 46] & 0xffff;
        if (dg) atomicAdd(&g_in[b * NC + tid], dg);
    } else if (tid >= 128 && tid < 128 + NC) {
        const int c = tid - 128;
        int cx = 0;
        for (int tt = 0; tt < NC; ++tt) {
            const int bin = c * NC + tt;
            cx += (s_pair[bin >> 1] >> ((bin & 1) << 4)) & 0xffff;
        }
        if (cx) atomicAdd(&g_cx[b * NC + c], cx);
    }
}

__global__ __launch_bounds__(64) void finalize_kernel(const int* __restrict__ g_cx,
                                                      const int* __restrict__ g_ct,
                                                      const int* __restrict__ g_in,
                                                      const float* __restrict__ smooth,
                                                      float* __restrict__ out) {
    const int b = blockIdx.x;
    const int lane = threadIdx.x;  // 0..63
    const float s = smooth[0];
    float acc = 0.0f;
    for (int c = lane; c < NC; c += 64) {
        const float in = (float)g_in[b * NC + c];
        const float un = (float)(g_cx[b * NC + c] + g_ct[b * NC + c]) - in;
        acc += (in + s) / (un + s);
    }
#pragma unroll
    for (int off = 32; off > 0; off >>= 1)
        acc += __shfl_down(acc, off, 64);
    if (lane == 0) out[b] = acc / (float)NC;
}

extern "C" void kernel_launch(void* const* d_in, const int* in_sizes, int n_in,
                              void* d_out, int out_size, void* d_ws, size_t ws_size,
                              hipStream_t stream) {
    const int* x = (const int*)d_in[0];
    const int* t = (const int*)d_in[1];
    const float* smooth = (const float*)d_in[2];
    float* out = (float*)d_out;

    int* g_cx = (int*)d_ws;                   // NB*NC
    int* g_ct = g_cx + NB * NC;               // NB*NC
    int* g_in = g_ct + NB * NC;               // NB*NC

    hipMemsetAsync(d_ws, 0, 3 * NB * NC * sizeof(int), stream);

    dim3 grid(GRID_X, NB);  // 64 x 32 = 2048 blocks (3/CU resident)
    hist_kernel<<<grid, THREADS, 0, stream>>>(x, t, g_cx, g_ct, g_in);
    finalize_kernel<<<NB, 64, 0, stream>>>(g_cx, g_ct, g_in, smooth, out);
}